// Round 12
// baseline (189.200 us; speedup 1.0000x reference)
//
#include <hip/hip_runtime.h>
#include <hip/hip_fp16.h>
#include <math.h>

// Problem constants (from reference)
constexpr int Nn  = 50000;   // nodes
constexpr int FIN = 128;     // input features
constexpr int NH  = 8;       // heads
constexpr int FO  = 16;      // features per head
constexpr int HF  = 128;     // NH*FO
constexpr int NWR = 272;     // Wh rows: Wp(128) | Wskip(128) | Va_src(8) | Va_trg(8)
constexpr int NSTRIPE = Nn / 16;                // 3125 node stripes
constexpr int NSCAN = (Nn + 255) / 256;         // 196 scan blocks

typedef _Float16 f16x8 __attribute__((ext_vector_type(8)));
typedef float    f32x4 __attribute__((ext_vector_type(4)));

// ---------------------------------------------------------------------------
// Weight prep: Wh[272][128] f16 (rows: Wp | Wskip | Va_src | Va_trg),
// ctp[h] = <Wt[h,:], a_tp[h,:]> in block 0. Must precede k_node.
// ---------------------------------------------------------------------------
__global__ __launch_bounds__(256) void k_prep(
    const float* __restrict__ Wp, const float* __restrict__ Wskip,
    const float* __restrict__ a_src, const float* __restrict__ a_trg,
    const float* __restrict__ Wt, const float* __restrict__ a_tp,
    _Float16* __restrict__ Wh, float* __restrict__ ctp)
{
    if (blockIdx.x == 0 && threadIdx.x < NH) {
        int h = threadIdx.x;
        float s = 0.f;
        #pragma unroll
        for (int f = 0; f < FO; ++f) s += Wt[h * FO + f] * a_tp[h * FO + f];
        ctp[h] = s;
    }
    const int o = blockIdx.x * 2 + (threadIdx.x >> 7);  // 0..271
    const int k = threadIdx.x & 127;
    float v;
    if (o < 128)      v = Wp[o * FIN + k];
    else if (o < 256) v = Wskip[(o - 128) * FIN + k];
    else if (o < 264) {
        const int h = o - 256;
        float s = 0.f;
        #pragma unroll
        for (int f = 0; f < FO; ++f)
            s += a_src[h * FO + f] * Wp[(h * FO + f) * FIN + k];
        v = s;
    } else {
        const int h = o - 264;
        float s = 0.f;
        #pragma unroll
        for (int f = 0; f < FO; ++f)
            s += a_trg[h * FO + f] * Wp[(h * FO + f) * FIN + k];
        v = s;
    }
    Wh[o * FIN + k] = (_Float16)v;
}

// ---------------------------------------------------------------------------
// CSR degree count (by target)
// ---------------------------------------------------------------------------
__global__ __launch_bounds__(256) void k_count(const int* __restrict__ trg,
                                               int* __restrict__ deg, int E)
{
    int e4 = blockIdx.x * 256 + threadIdx.x;
    if (e4 * 4 < E) {
        int4 t = reinterpret_cast<const int4*>(trg)[e4];
        atomicAdd(&deg[t.x], 1);
        atomicAdd(&deg[t.y], 1);
        atomicAdd(&deg[t.z], 1);
        atomicAdd(&deg[t.w], 1);
    }
}

// ---------------------------------------------------------------------------
// Node GEMM via MFMA f16, 4 waves per 16-node stripe (one 256-thr block).
// Wave w computes output tiles w*4 .. w*4+3 of C = x @ Wh^T; wave 3 also
// computes the score tile (named acc16 — all acc indices compile-time).
// The 4 waves re-load the same x rows (same-CU L1 hits).
// Epilogue: projA[n][h][f] f16 node-major, out = skip + bias, s_pair.
// ---------------------------------------------------------------------------
__global__ __launch_bounds__(256) void k_node(
    const float* __restrict__ x, const _Float16* __restrict__ Wh,
    const float* __restrict__ bias,
    __half* __restrict__ projA, float* __restrict__ out,
    float* __restrict__ s_pair)
{
    const int n0 = blockIdx.x * 16;            // 3125 * 16 = 50000 exactly
    const int w  = threadIdx.x >> 6;           // wave 0..3 (uniform per wave)
    const int l  = threadIdx.x & 63;
    const int lr = l & 15;
    const int kb = l >> 4;                     // k-block 0..3
    const int t0 = w * 4;                      // first tile of this wave

    // A fragments (shared addresses across the block's 4 waves -> L1 hits)
    f16x8 a[4];
    const float* xr = x + (size_t)(n0 + lr) * FIN + kb * 8;
    #pragma unroll
    for (int ks = 0; ks < 4; ++ks) {
        float4 u0 = *reinterpret_cast<const float4*>(xr + ks * 32);
        float4 u1 = *reinterpret_cast<const float4*>(xr + ks * 32 + 4);
        a[ks][0] = (_Float16)u0.x; a[ks][1] = (_Float16)u0.y;
        a[ks][2] = (_Float16)u0.z; a[ks][3] = (_Float16)u0.w;
        a[ks][4] = (_Float16)u1.x; a[ks][5] = (_Float16)u1.y;
        a[ks][6] = (_Float16)u1.z; a[ks][7] = (_Float16)u1.w;
    }

    f32x4 acc[4];
    #pragma unroll
    for (int i = 0; i < 4; ++i) acc[i] = (f32x4){0.f, 0.f, 0.f, 0.f};
    f32x4 acc16 = (f32x4){0.f, 0.f, 0.f, 0.f};

    const _Float16* wb = Wh + (size_t)lr * FIN + kb * 8;
    #pragma unroll
    for (int i = 0; i < 4; ++i) {
        const _Float16* wt = wb + (size_t)(t0 + i) * 16 * FIN;
        #pragma unroll
        for (int ks = 0; ks < 4; ++ks) {
            f16x8 b = *reinterpret_cast<const f16x8*>(wt + ks * 32);
            acc[i] = __builtin_amdgcn_mfma_f32_16x16x32_f16(a[ks], b, acc[i], 0, 0, 0);
        }
    }
    if (w == 3) {
        const _Float16* wt = wb + (size_t)16 * 16 * FIN;
        #pragma unroll
        for (int ks = 0; ks < 4; ++ks) {
            f16x8 b = *reinterpret_cast<const f16x8*>(wt + ks * 32);
            acc16 = __builtin_amdgcn_mfma_f32_16x16x32_f16(a[ks], b, acc16, 0, 0, 0);
        }
    }

    #pragma unroll
    for (int r = 0; r < 4; ++r) {
        const int n = n0 + kb * 4 + r;
        if (t0 < 8) {
            // waves 0,1: proj heads, node-major f16
            #pragma unroll
            for (int i = 0; i < 4; ++i)
                projA[(size_t)n * HF + (t0 + i) * FO + lr] =
                    __float2half_rn(acc[i][r]);
        } else {
            // waves 2,3: skip + bias -> output accumulator
            #pragma unroll
            for (int i = 0; i < 4; ++i) {
                const int o = (t0 + i - 8) * 16 + lr;
                out[(size_t)n * HF + o] = acc[i][r] + bias[o];
            }
        }
        if (w == 3) s_pair[n * 16 + lr] = acc16[r];
    }
}

// ---------------------------------------------------------------------------
// Scan: per-block sums, then fused (redundant block-scan of partials) +
// per-element exclusive scan -> pos.
// ---------------------------------------------------------------------------
__global__ __launch_bounds__(256) void k_scan1(const int* __restrict__ deg,
                                               int* __restrict__ partial)
{
    __shared__ int lds[256];
    int t = threadIdx.x, i = blockIdx.x * 256 + t;
    lds[t] = (i < Nn) ? deg[i] : 0;
    __syncthreads();
    for (int off = 128; off > 0; off >>= 1) {
        if (t < off) lds[t] += lds[t + off];
        __syncthreads();
    }
    if (t == 0) partial[blockIdx.x] = lds[0];
}

__global__ __launch_bounds__(256) void k_scan3(const int* __restrict__ deg,
                                               const int* __restrict__ partial,
                                               int* __restrict__ pos)
{
    __shared__ int lds[256], lds2[256];
    const int t = threadIdx.x;
    const int i = blockIdx.x * 256 + t;
    lds2[t] = (t < NSCAN) ? partial[t] : 0;
    __syncthreads();
    for (int off = 1; off < 256; off <<= 1) {
        int u = (t >= off) ? lds2[t - off] : 0;
        __syncthreads();
        lds2[t] += u;
        __syncthreads();
    }
    const int base = (blockIdx.x == 0) ? 0 : lds2[blockIdx.x - 1];
    int v = (i < Nn) ? deg[i] : 0;
    lds[t] = v;
    __syncthreads();
    for (int off = 1; off < 256; off <<= 1) {
        int u = (t >= off) ? lds[t - off] : 0;
        __syncthreads();
        lds[t] += u;
        __syncthreads();
    }
    if (i < Nn) pos[i] = base + lds[t] - v;
}

// fill: pos[n] bumps exclusive -> inclusive; row n spans
// [ (n ? pos[n-1] : 0), pos[n] ).  spk = src(16b) | f16(prob)(16b), 4B/edge.
__global__ __launch_bounds__(256) void k_fill(
    const int* __restrict__ src, const int* __restrict__ trg,
    const float* __restrict__ prob, int* __restrict__ pos,
    unsigned int* __restrict__ spk, int E)
{
    int e4 = blockIdx.x * blockDim.x + threadIdx.x;
    if (e4 * 4 >= E) return;
    int4   s4 = reinterpret_cast<const int4*>(src)[e4];
    int4   t4 = reinterpret_cast<const int4*>(trg)[e4];
    float4 p4 = reinterpret_cast<const float4*>(prob)[e4];
    int    sv[4] = {s4.x, s4.y, s4.z, s4.w};
    int    tv[4] = {t4.x, t4.y, t4.z, t4.w};
    float  pv[4] = {p4.x, p4.y, p4.z, p4.w};
    #pragma unroll
    for (int i = 0; i < 4; ++i) {
        int slot = atomicAdd(&pos[tv[i]], 1);
        spk[slot] = (unsigned int)sv[i] |
            ((unsigned int)__half_as_ushort(__float2half_rn(pv[i])) << 16);
    }
}

// ---------------------------------------------------------------------------
// Fused gather: one wave per node; lanes = 8 heads x 8 feature-pairs.
// All lanes share the node's edge range (zero divergence, zero shuffles).
// Per edge: spk dword (broadcast) + s_pair[s] gather + projA[s] 256B
// contiguous wave-read; score+exp inline. 4 independent chains for MLP.
// ---------------------------------------------------------------------------
__global__ __launch_bounds__(256) void k_gather(
    const unsigned int* __restrict__ spk, const int* __restrict__ pos,
    const float* __restrict__ s_pair, const float* __restrict__ ctp,
    const __half2* __restrict__ projA, float* __restrict__ out)
{
    const int wv   = threadIdx.x >> 6;
    const int n    = blockIdx.x * 4 + wv;      // 12500*4 = 50000 exactly
    const int lane = threadIdx.x & 63;
    const int h    = lane >> 3;                // head 0..7
    const int f2   = lane & 7;                 // feature pair 0..7

    const int jb = (n == 0) ? 0 : pos[n - 1];
    const int je = pos[n];
    const float st  = s_pair[n * 16 + 8 + h];
    const float cth = ctp[h];
    const float* __restrict__ ssl = s_pair + h;          // [s*16]
    const __half2* __restrict__ pA = projA + h * 8 + f2; // [s*64]

    float num0 = 0.f, num1 = 0.f, den = 0.f;
    int j = jb;
    for (; j + 3 < je; j += 4) {               // 4 independent chains
        const unsigned int pk0 = spk[j];
        const unsigned int pk1 = spk[j + 1];
        const unsigned int pk2 = spk[j + 2];
        const unsigned int pk3 = spk[j + 3];
        const int s0 = pk0 & 0xFFFF, s1 = pk1 & 0xFFFF;
        const int s2 = pk2 & 0xFFFF, s3 = pk3 & 0xFFFF;
        const float ss0 = ssl[s0 * 16], ss1 = ssl[s1 * 16];
        const float ss2 = ssl[s2 * 16], ss3 = ssl[s3 * 16];
        const __half2 g0 = pA[s0 * 64], g1 = pA[s1 * 64];
        const __half2 g2 = pA[s2 * 64], g3 = pA[s3 * 64];
        const float p0 = __half2float(__ushort_as_half((unsigned short)(pk0 >> 16)));
        const float p1 = __half2float(__ushort_as_half((unsigned short)(pk1 >> 16)));
        const float p2 = __half2float(__ushort_as_half((unsigned short)(pk2 >> 16)));
        const float p3 = __half2float(__ushort_as_half((unsigned short)(pk3 >> 16)));
        float sc0 = ss0 + st + cth * p0;
        float sc1 = ss1 + st + cth * p1;
        float sc2 = ss2 + st + cth * p2;
        float sc3 = ss3 + st + cth * p3;
        sc0 = fmaxf(sc0, 0.2f * sc0);          // leaky_relu(0.2)
        sc1 = fmaxf(sc1, 0.2f * sc1);
        sc2 = fmaxf(sc2, 0.2f * sc2);
        sc3 = fmaxf(sc3, 0.2f * sc3);
        const float ev0 = __expf(sc0), ev1 = __expf(sc1);
        const float ev2 = __expf(sc2), ev3 = __expf(sc3);
        const float2 G0 = __half22float2(g0), G1 = __half22float2(g1);
        const float2 G2 = __half22float2(g2), G3 = __half22float2(g3);
        den  += (ev0 + ev1) + (ev2 + ev3);
        num0 += ev0 * G0.x + ev1 * G1.x + ev2 * G2.x + ev3 * G3.x;
        num1 += ev0 * G0.y + ev1 * G1.y + ev2 * G2.y + ev3 * G3.y;
    }
    for (; j < je; ++j) {
        const unsigned int pk = spk[j];
        const int s = pk & 0xFFFF;
        const float p = __half2float(__ushort_as_half((unsigned short)(pk >> 16)));
        float sc = ssl[s * 16] + st + cth * p;
        sc = fmaxf(sc, 0.2f * sc);
        const float ev = __expf(sc);
        const float2 G = __half22float2(pA[s * 64]);
        den  += ev;
        num0 += ev * G.x;
        num1 += ev * G.y;
    }

    const float inv = 1.f / (den + 1e-16f);
    const int idx = n * HF + h * FO + f2 * 2;
    float2 o = *reinterpret_cast<const float2*>(&out[idx]);  // skip+bias
    float v0 = o.x + num0 * inv;
    float v1 = o.y + num1 * inv;
    v0 = v0 > 0.f ? v0 : expm1f(v0);
    v1 = v1 > 0.f ? v1 : expm1f(v1);
    *reinterpret_cast<float2*>(&out[idx]) = make_float2(v0, v1);
}

// ---------------------------------------------------------------------------
extern "C" void kernel_launch(void* const* d_in, const int* in_sizes, int n_in,
                              void* d_out, int out_size, void* d_ws, size_t ws_size,
                              hipStream_t stream)
{
    const float* x     = (const float*)d_in[0];
    const int*   ei    = (const int*)d_in[1];
    const float* prob  = (const float*)d_in[2];
    const float* Wp    = (const float*)d_in[3];
    const float* Wt    = (const float*)d_in[4];
    const float* a_src = (const float*)d_in[5];
    const float* a_trg = (const float*)d_in[6];
    const float* a_tp  = (const float*)d_in[7];
    const float* Wskip = (const float*)d_in[8];
    const float* bias  = (const float*)d_in[9];
    float* out = (float*)d_out;

    const int E = in_sizes[2];        // edge_prob element count = E
    const int* src = ei;              // edge_index row 0
    const int* trg = ei + E;          // edge_index row 1

    // Workspace layout (~20 MB); all blocks 16B-aligned by construction
    char* wsb = (char*)d_ws;
    __half* projA  = (__half*)wsb;                      // Nn*HF f16 (12.8 MB)
    float* s_pair  = (float*)(wsb + (size_t)Nn*HF*2);   // Nn*16     (3.2 MB)
    float* ctp     = s_pair + (size_t)Nn * 16;          // 16 floats
    _Float16* Wh   = (_Float16*)(ctp + 16);             // 272*128   (68 KB)
    unsigned int* spk = (unsigned int*)(Wh + (size_t)NWR * FIN); // E (3.2 MB)
    int*   deg     = (int*)(spk + E);                   // Nn
    int*   pos     = deg + Nn;                          // Nn
    int*   partial = pos + Nn;                          // NSCAN (pad 256)

    hipMemsetAsync(deg, 0, (size_t)Nn * sizeof(int), stream);
    k_prep<<<NWR / 2, 256, 0, stream>>>(Wp, Wskip, a_src, a_trg, Wt, a_tp,
                                        Wh, ctp);
    k_count<<<(E / 4 + 255) / 256, 256, 0, stream>>>(trg, deg, E);
    k_node<<<NSTRIPE, 256, 0, stream>>>(x, Wh, bias, projA, out, s_pair);
    k_scan1<<<NSCAN, 256, 0, stream>>>(deg, partial);
    k_scan3<<<NSCAN, 256, 0, stream>>>(deg, partial, pos);
    k_fill<<<(E / 4 + 255) / 256, 256, 0, stream>>>(src, trg, prob, pos, spk, E);
    k_gather<<<Nn / 4, 256, 0, stream>>>(spk, pos, s_pair, ctp,
                                         (const __half2*)projA, out);
}

// Round 13
// 180.418 us; speedup vs baseline: 1.0487x; 1.0487x over previous
//
#include <hip/hip_runtime.h>
#include <hip/hip_fp16.h>
#include <math.h>

// Problem constants (from reference)
constexpr int Nn  = 50000;   // nodes
constexpr int FIN = 128;     // input features
constexpr int NH  = 8;       // heads
constexpr int FO  = 16;      // features per head
constexpr int HF  = 128;     // NH*FO
constexpr int NWR = 272;     // Wh rows: Wp(128) | Wskip(128) | Va_src(8) | Va_trg(8)
constexpr int NPREP = NWR / 2;                  // 136 prep blocks (2 rows each)
constexpr int NSTRIPE = Nn / 16;                // 3125 node stripes
constexpr int NSCAN = (Nn + 255) / 256;         // 196 scan blocks

typedef _Float16 f16x8 __attribute__((ext_vector_type(8)));
typedef float    f32x4 __attribute__((ext_vector_type(4)));

// ---------------------------------------------------------------------------
// Fused prep + count (disjoint: prep writes Wh/ctp; count reads trg -> deg).
//   blocks [0, NPREP)          : Wh[272][128] f16 (2 rows/block) + ctp (blk 0)
//   blocks [NPREP, NPREP+nbC)  : CSR degree count (4 edges/thread, f&f atomics)
// ---------------------------------------------------------------------------
__global__ __launch_bounds__(256) void k_pc(
    const float* __restrict__ Wp, const float* __restrict__ Wskip,
    const float* __restrict__ a_src, const float* __restrict__ a_trg,
    const float* __restrict__ Wt, const float* __restrict__ a_tp,
    _Float16* __restrict__ Wh, float* __restrict__ ctp,
    const int* __restrict__ trg, int* __restrict__ deg, int E)
{
    const int bid = blockIdx.x;
    if (bid < NPREP) {
        if (bid == 0 && threadIdx.x < NH) {
            int h = threadIdx.x;
            float s = 0.f;
            #pragma unroll
            for (int f = 0; f < FO; ++f) s += Wt[h * FO + f] * a_tp[h * FO + f];
            ctp[h] = s;
        }
        const int o = bid * 2 + (threadIdx.x >> 7);  // 0..271
        const int k = threadIdx.x & 127;
        float v;
        if (o < 128)      v = Wp[o * FIN + k];
        else if (o < 256) v = Wskip[(o - 128) * FIN + k];
        else if (o < 264) {
            const int h = o - 256;
            float s = 0.f;
            #pragma unroll
            for (int f = 0; f < FO; ++f)
                s += a_src[h * FO + f] * Wp[(h * FO + f) * FIN + k];
            v = s;
        } else {
            const int h = o - 264;
            float s = 0.f;
            #pragma unroll
            for (int f = 0; f < FO; ++f)
                s += a_trg[h * FO + f] * Wp[(h * FO + f) * FIN + k];
            v = s;
        }
        Wh[o * FIN + k] = (_Float16)v;
        return;
    }

    int e4 = (bid - NPREP) * 256 + threadIdx.x;
    if (e4 * 4 < E) {
        int4 t = reinterpret_cast<const int4*>(trg)[e4];
        atomicAdd(&deg[t.x], 1);
        atomicAdd(&deg[t.y], 1);
        atomicAdd(&deg[t.z], 1);
        atomicAdd(&deg[t.w], 1);
    }
}

// ---------------------------------------------------------------------------
// Scan: per-block sums, then fused (redundant block-scan of partials) +
// per-element exclusive scan -> pos.
// ---------------------------------------------------------------------------
__global__ __launch_bounds__(256) void k_scan1(const int* __restrict__ deg,
                                               int* __restrict__ partial)
{
    __shared__ int lds[256];
    int t = threadIdx.x, i = blockIdx.x * 256 + t;
    lds[t] = (i < Nn) ? deg[i] : 0;
    __syncthreads();
    for (int off = 128; off > 0; off >>= 1) {
        if (t < off) lds[t] += lds[t + off];
        __syncthreads();
    }
    if (t == 0) partial[blockIdx.x] = lds[0];
}

__global__ __launch_bounds__(256) void k_scan3(const int* __restrict__ deg,
                                               const int* __restrict__ partial,
                                               int* __restrict__ pos)
{
    __shared__ int lds[256], lds2[256];
    const int t = threadIdx.x;
    const int i = blockIdx.x * 256 + t;
    lds2[t] = (t < NSCAN) ? partial[t] : 0;
    __syncthreads();
    for (int off = 1; off < 256; off <<= 1) {
        int u = (t >= off) ? lds2[t - off] : 0;
        __syncthreads();
        lds2[t] += u;
        __syncthreads();
    }
    const int base = (blockIdx.x == 0) ? 0 : lds2[blockIdx.x - 1];
    int v = (i < Nn) ? deg[i] : 0;
    lds[t] = v;
    __syncthreads();
    for (int off = 1; off < 256; off <<= 1) {
        int u = (t >= off) ? lds[t - off] : 0;
        __syncthreads();
        lds[t] += u;
        __syncthreads();
    }
    if (i < Nn) pos[i] = base + lds[t] - v;
}

// ---------------------------------------------------------------------------
// Fused fill + node GEMM (disjoint: fill reads src/trg/prob, RMWs pos,
// writes spk; node reads x/Wh/bias, writes projA/out/s_pair).
// Fill blocks FIRST (atomic-latency long pole starts immediately); node
// blocks after — their MFMA/VMEM work fills the fill waves' latency bubbles.
//
// fill: pos[n] bumps exclusive -> inclusive; row n spans
// [ (n ? pos[n-1] : 0), pos[n] ).  spk = src(16b) | f16(prob)(16b), 4B/edge.
// node: 4 waves per 16-node stripe; wave w computes tiles w*4..w*4+3 of
// C = x @ Wh^T; wave 3 also the score tile (acc16; static indices).
// ---------------------------------------------------------------------------
__global__ __launch_bounds__(256) void k_fn(
    const int* __restrict__ src, const int* __restrict__ trg,
    const float* __restrict__ prob, int* __restrict__ pos,
    unsigned int* __restrict__ spk,
    const float* __restrict__ x, const _Float16* __restrict__ Wh,
    const float* __restrict__ bias,
    __half* __restrict__ projA, float* __restrict__ out,
    float* __restrict__ s_pair, int E, int nbFill)
{
    const int bid = blockIdx.x;

    if (bid < nbFill) {
        int e4 = bid * 256 + threadIdx.x;
        if (e4 * 4 < E) {
            int4   s4 = reinterpret_cast<const int4*>(src)[e4];
            int4   t4 = reinterpret_cast<const int4*>(trg)[e4];
            float4 p4 = reinterpret_cast<const float4*>(prob)[e4];
            int    sv[4] = {s4.x, s4.y, s4.z, s4.w};
            int    tv[4] = {t4.x, t4.y, t4.z, t4.w};
            float  pv[4] = {p4.x, p4.y, p4.z, p4.w};
            #pragma unroll
            for (int i = 0; i < 4; ++i) {
                int slot = atomicAdd(&pos[tv[i]], 1);
                spk[slot] = (unsigned int)sv[i] |
                    ((unsigned int)__half_as_ushort(__float2half_rn(pv[i])) << 16);
            }
        }
        return;
    }

    // ---- node GEMM ----
    const int n0 = (bid - nbFill) * 16;        // 3125 stripes * 16 = 50000
    const int w  = threadIdx.x >> 6;           // wave 0..3 (uniform per wave)
    const int l  = threadIdx.x & 63;
    const int lr = l & 15;
    const int kb = l >> 4;                     // k-block 0..3
    const int t0 = w * 4;                      // first tile of this wave

    f16x8 a[4];
    const float* xr = x + (size_t)(n0 + lr) * FIN + kb * 8;
    #pragma unroll
    for (int ks = 0; ks < 4; ++ks) {
        float4 u0 = *reinterpret_cast<const float4*>(xr + ks * 32);
        float4 u1 = *reinterpret_cast<const float4*>(xr + ks * 32 + 4);
        a[ks][0] = (_Float16)u0.x; a[ks][1] = (_Float16)u0.y;
        a[ks][2] = (_Float16)u0.z; a[ks][3] = (_Float16)u0.w;
        a[ks][4] = (_Float16)u1.x; a[ks][5] = (_Float16)u1.y;
        a[ks][6] = (_Float16)u1.z; a[ks][7] = (_Float16)u1.w;
    }

    f32x4 acc[4];
    #pragma unroll
    for (int i = 0; i < 4; ++i) acc[i] = (f32x4){0.f, 0.f, 0.f, 0.f};
    f32x4 acc16 = (f32x4){0.f, 0.f, 0.f, 0.f};

    const _Float16* wb = Wh + (size_t)lr * FIN + kb * 8;
    #pragma unroll
    for (int i = 0; i < 4; ++i) {
        const _Float16* wt = wb + (size_t)(t0 + i) * 16 * FIN;
        #pragma unroll
        for (int ks = 0; ks < 4; ++ks) {
            f16x8 b = *reinterpret_cast<const f16x8*>(wt + ks * 32);
            acc[i] = __builtin_amdgcn_mfma_f32_16x16x32_f16(a[ks], b, acc[i], 0, 0, 0);
        }
    }
    if (w == 3) {
        const _Float16* wt = wb + (size_t)16 * 16 * FIN;
        #pragma unroll
        for (int ks = 0; ks < 4; ++ks) {
            f16x8 b = *reinterpret_cast<const f16x8*>(wt + ks * 32);
            acc16 = __builtin_amdgcn_mfma_f32_16x16x32_f16(a[ks], b, acc16, 0, 0, 0);
        }
    }

    #pragma unroll
    for (int r = 0; r < 4; ++r) {
        const int n = n0 + kb * 4 + r;
        if (t0 < 8) {
            #pragma unroll
            for (int i = 0; i < 4; ++i)
                projA[(size_t)n * HF + (t0 + i) * FO + lr] =
                    __float2half_rn(acc[i][r]);
        } else {
            #pragma unroll
            for (int i = 0; i < 4; ++i) {
                const int o = (t0 + i - 8) * 16 + lr;
                out[(size_t)n * HF + o] = acc[i][r] + bias[o];
            }
        }
        if (w == 3) s_pair[n * 16 + lr] = acc16[r];
    }
}

// ---------------------------------------------------------------------------
// Fused gather: one wave per node; lanes = 8 heads x 8 feature-pairs.
// All lanes share the node's edge range (zero divergence, zero shuffles).
// Per edge: spk dword (broadcast) + s_pair[s] gather + projA[s] 256B
// contiguous wave-read; score+exp inline. 4 independent chains for MLP.
// ---------------------------------------------------------------------------
__global__ __launch_bounds__(256) void k_gather(
    const unsigned int* __restrict__ spk, const int* __restrict__ pos,
    const float* __restrict__ s_pair, const float* __restrict__ ctp,
    const __half2* __restrict__ projA, float* __restrict__ out)
{
    const int wv   = threadIdx.x >> 6;
    const int n    = blockIdx.x * 4 + wv;      // 12500*4 = 50000 exactly
    const int lane = threadIdx.x & 63;
    const int h    = lane >> 3;                // head 0..7
    const int f2   = lane & 7;                 // feature pair 0..7

    const int jb = (n == 0) ? 0 : pos[n - 1];
    const int je = pos[n];
    const float st  = s_pair[n * 16 + 8 + h];
    const float cth = ctp[h];
    const float* __restrict__ ssl = s_pair + h;          // [s*16]
    const __half2* __restrict__ pA = projA + h * 8 + f2; // [s*64]

    float num0 = 0.f, num1 = 0.f, den = 0.f;
    int j = jb;
    for (; j + 3 < je; j += 4) {               // 4 independent chains
        const unsigned int pk0 = spk[j];
        const unsigned int pk1 = spk[j + 1];
        const unsigned int pk2 = spk[j + 2];
        const unsigned int pk3 = spk[j + 3];
        const int s0 = pk0 & 0xFFFF, s1 = pk1 & 0xFFFF;
        const int s2 = pk2 & 0xFFFF, s3 = pk3 & 0xFFFF;
        const float ss0 = ssl[s0 * 16], ss1 = ssl[s1 * 16];
        const float ss2 = ssl[s2 * 16], ss3 = ssl[s3 * 16];
        const __half2 g0 = pA[s0 * 64], g1 = pA[s1 * 64];
        const __half2 g2 = pA[s2 * 64], g3 = pA[s3 * 64];
        const float p0 = __half2float(__ushort_as_half((unsigned short)(pk0 >> 16)));
        const float p1 = __half2float(__ushort_as_half((unsigned short)(pk1 >> 16)));
        const float p2 = __half2float(__ushort_as_half((unsigned short)(pk2 >> 16)));
        const float p3 = __half2float(__ushort_as_half((unsigned short)(pk3 >> 16)));
        float sc0 = ss0 + st + cth * p0;
        float sc1 = ss1 + st + cth * p1;
        float sc2 = ss2 + st + cth * p2;
        float sc3 = ss3 + st + cth * p3;
        sc0 = fmaxf(sc0, 0.2f * sc0);          // leaky_relu(0.2)
        sc1 = fmaxf(sc1, 0.2f * sc1);
        sc2 = fmaxf(sc2, 0.2f * sc2);
        sc3 = fmaxf(sc3, 0.2f * sc3);
        const float ev0 = __expf(sc0), ev1 = __expf(sc1);
        const float ev2 = __expf(sc2), ev3 = __expf(sc3);
        const float2 G0 = __half22float2(g0), G1 = __half22float2(g1);
        const float2 G2 = __half22float2(g2), G3 = __half22float2(g3);
        den  += (ev0 + ev1) + (ev2 + ev3);
        num0 += ev0 * G0.x + ev1 * G1.x + ev2 * G2.x + ev3 * G3.x;
        num1 += ev0 * G0.y + ev1 * G1.y + ev2 * G2.y + ev3 * G3.y;
    }
    for (; j < je; ++j) {
        const unsigned int pk = spk[j];
        const int s = pk & 0xFFFF;
        const float p = __half2float(__ushort_as_half((unsigned short)(pk >> 16)));
        float sc = ssl[s * 16] + st + cth * p;
        sc = fmaxf(sc, 0.2f * sc);
        const float ev = __expf(sc);
        const float2 G = __half22float2(pA[s * 64]);
        den  += ev;
        num0 += ev * G.x;
        num1 += ev * G.y;
    }

    const float inv = 1.f / (den + 1e-16f);
    const int idx = n * HF + h * FO + f2 * 2;
    float2 o = *reinterpret_cast<const float2*>(&out[idx]);  // skip+bias
    float v0 = o.x + num0 * inv;
    float v1 = o.y + num1 * inv;
    v0 = v0 > 0.f ? v0 : expm1f(v0);
    v1 = v1 > 0.f ? v1 : expm1f(v1);
    *reinterpret_cast<float2*>(&out[idx]) = make_float2(v0, v1);
}

// ---------------------------------------------------------------------------
extern "C" void kernel_launch(void* const* d_in, const int* in_sizes, int n_in,
                              void* d_out, int out_size, void* d_ws, size_t ws_size,
                              hipStream_t stream)
{
    const float* x     = (const float*)d_in[0];
    const int*   ei    = (const int*)d_in[1];
    const float* prob  = (const float*)d_in[2];
    const float* Wp    = (const float*)d_in[3];
    const float* Wt    = (const float*)d_in[4];
    const float* a_src = (const float*)d_in[5];
    const float* a_trg = (const float*)d_in[6];
    const float* a_tp  = (const float*)d_in[7];
    const float* Wskip = (const float*)d_in[8];
    const float* bias  = (const float*)d_in[9];
    float* out = (float*)d_out;

    const int E = in_sizes[2];        // edge_prob element count = E
    const int* src = ei;              // edge_index row 0
    const int* trg = ei + E;          // edge_index row 1

    // Workspace layout (~20 MB); all blocks 16B-aligned by construction
    char* wsb = (char*)d_ws;
    __half* projA  = (__half*)wsb;                      // Nn*HF f16 (12.8 MB)
    float* s_pair  = (float*)(wsb + (size_t)Nn*HF*2);   // Nn*16     (3.2 MB)
    float* ctp     = s_pair + (size_t)Nn * 16;          // 16 floats
    _Float16* Wh   = (_Float16*)(ctp + 16);             // 272*128   (68 KB)
    unsigned int* spk = (unsigned int*)(Wh + (size_t)NWR * FIN); // E (3.2 MB)
    int*   deg     = (int*)(spk + E);                   // Nn
    int*   pos     = deg + Nn;                          // Nn
    int*   partial = pos + Nn;                          // NSCAN (pad 256)

    const int nbCount = (E / 4 + 255) / 256;            // 782 @ E=800000
    const int nbFill  = nbCount;

    hipMemsetAsync(deg, 0, (size_t)Nn * sizeof(int), stream);
    k_pc<<<NPREP + nbCount, 256, 0, stream>>>(Wp, Wskip, a_src, a_trg, Wt,
                                              a_tp, Wh, ctp, trg, deg, E);
    k_scan1<<<NSCAN, 256, 0, stream>>>(deg, partial);
    k_scan3<<<NSCAN, 256, 0, stream>>>(deg, partial, pos);
    k_fn<<<nbFill + NSTRIPE, 256, 0, stream>>>(src, trg, prob, pos, spk,
                                               x, Wh, bias, projA, out,
                                               s_pair, E, nbFill);
    k_gather<<<Nn / 4, 256, 0, stream>>>(spk, pos, s_pair, ctp,
                                         (const __half2*)projA, out);
}

// Round 14
// 178.025 us; speedup vs baseline: 1.0628x; 1.0134x over previous
//
#include <hip/hip_runtime.h>
#include <hip/hip_fp16.h>
#include <math.h>

// Problem constants (from reference)
constexpr int Nn  = 50000;   // nodes
constexpr int FIN = 128;     // input features
constexpr int NH  = 8;       // heads
constexpr int FO  = 16;      // features per head
constexpr int HF  = 128;     // NH*FO
constexpr int NWR = 272;     // Wh rows: Wp(128) | Wskip(128) | Va_src(8) | Va_trg(8)
constexpr int NPREP = NWR / 2;                  // 136 prep blocks (2 rows each)
constexpr int NSTRIPE = Nn / 16;                // 3125 node stripes
constexpr int NSCAN = (Nn + 255) / 256;         // 196 scan blocks

typedef _Float16 f16x8 __attribute__((ext_vector_type(8)));
typedef float    f32x4 __attribute__((ext_vector_type(4)));

// ---------------------------------------------------------------------------
// Fused prep + count.
//   blocks [0, NPREP)   : Wh[272][128] f16 (2 rows/block) + ctp (block 0)
//   blocks [NPREP, ...) : CSR degree count, ONE edge per thread (64
//                         independent atomics per wave -> single waitcnt,
//                         no serial atomic chain)
// ---------------------------------------------------------------------------
__global__ __launch_bounds__(256) void k_pc(
    const float* __restrict__ Wp, const float* __restrict__ Wskip,
    const float* __restrict__ a_src, const float* __restrict__ a_trg,
    const float* __restrict__ Wt, const float* __restrict__ a_tp,
    _Float16* __restrict__ Wh, float* __restrict__ ctp,
    const int* __restrict__ trg, int* __restrict__ deg, int E)
{
    const int bid = blockIdx.x;
    if (bid < NPREP) {
        if (bid == 0 && threadIdx.x < NH) {
            int h = threadIdx.x;
            float s = 0.f;
            #pragma unroll
            for (int f = 0; f < FO; ++f) s += Wt[h * FO + f] * a_tp[h * FO + f];
            ctp[h] = s;
        }
        const int o = bid * 2 + (threadIdx.x >> 7);  // 0..271
        const int k = threadIdx.x & 127;
        float v;
        if (o < 128)      v = Wp[o * FIN + k];
        else if (o < 256) v = Wskip[(o - 128) * FIN + k];
        else if (o < 264) {
            const int h = o - 256;
            float s = 0.f;
            #pragma unroll
            for (int f = 0; f < FO; ++f)
                s += a_src[h * FO + f] * Wp[(h * FO + f) * FIN + k];
            v = s;
        } else {
            const int h = o - 264;
            float s = 0.f;
            #pragma unroll
            for (int f = 0; f < FO; ++f)
                s += a_trg[h * FO + f] * Wp[(h * FO + f) * FIN + k];
            v = s;
        }
        Wh[o * FIN + k] = (_Float16)v;
        return;
    }

    int e = (bid - NPREP) * 256 + threadIdx.x;
    if (e < E) atomicAdd(&deg[trg[e]], 1);
}

// ---------------------------------------------------------------------------
// Scan: per-block sums, then fused (redundant block-scan of partials) +
// per-element exclusive scan -> pos.
// ---------------------------------------------------------------------------
__global__ __launch_bounds__(256) void k_scan1(const int* __restrict__ deg,
                                               int* __restrict__ partial)
{
    __shared__ int lds[256];
    int t = threadIdx.x, i = blockIdx.x * 256 + t;
    lds[t] = (i < Nn) ? deg[i] : 0;
    __syncthreads();
    for (int off = 128; off > 0; off >>= 1) {
        if (t < off) lds[t] += lds[t + off];
        __syncthreads();
    }
    if (t == 0) partial[blockIdx.x] = lds[0];
}

__global__ __launch_bounds__(256) void k_scan3(const int* __restrict__ deg,
                                               const int* __restrict__ partial,
                                               int* __restrict__ pos)
{
    __shared__ int lds[256], lds2[256];
    const int t = threadIdx.x;
    const int i = blockIdx.x * 256 + t;
    lds2[t] = (t < NSCAN) ? partial[t] : 0;
    __syncthreads();
    for (int off = 1; off < 256; off <<= 1) {
        int u = (t >= off) ? lds2[t - off] : 0;
        __syncthreads();
        lds2[t] += u;
        __syncthreads();
    }
    const int base = (blockIdx.x == 0) ? 0 : lds2[blockIdx.x - 1];
    int v = (i < Nn) ? deg[i] : 0;
    lds[t] = v;
    __syncthreads();
    for (int off = 1; off < 256; off <<= 1) {
        int u = (t >= off) ? lds[t - off] : 0;
        __syncthreads();
        lds[t] += u;
        __syncthreads();
    }
    if (i < Nn) pos[i] = base + lds[t] - v;
}

// ---------------------------------------------------------------------------
// Fused fill + node GEMM, INTERLEAVED by bid parity so both block types are
// co-resident on every CU for the whole dispatch (concatenated ranges run
// phase-serial — R13 lesson):
//   even bid : node stripe bid>>1   (3125 stripes)
//   odd  bid : fill chunk  bid>>1   (3125 chunks, ONE edge per thread)
// Disjoint resources: fill reads src/trg/prob, RMWs pos, writes spk; node
// reads x/Wh/bias, writes projA/out/s_pair.
//
// fill: pos[n] bumps exclusive -> inclusive; row n spans
// [ (n ? pos[n-1] : 0), pos[n] ).  spk = src(16b) | f16(prob)(16b), 4B/edge.
// node: 4 waves per 16-node stripe; wave w computes tiles w*4..w*4+3 of
// C = x @ Wh^T; wave 3 also the score tile (acc16; static indices).
// ---------------------------------------------------------------------------
__global__ __launch_bounds__(256) void k_fn(
    const int* __restrict__ src, const int* __restrict__ trg,
    const float* __restrict__ prob, int* __restrict__ pos,
    unsigned int* __restrict__ spk,
    const float* __restrict__ x, const _Float16* __restrict__ Wh,
    const float* __restrict__ bias,
    __half* __restrict__ projA, float* __restrict__ out,
    float* __restrict__ s_pair, int E)
{
    const int bid = blockIdx.x;

    if (bid & 1) {
        // ---- fill: one edge per thread ----
        int e = (bid >> 1) * 256 + threadIdx.x;
        if (e < E) {
            int s = src[e], t = trg[e];
            float p = prob[e];
            int slot = atomicAdd(&pos[t], 1);
            spk[slot] = (unsigned int)s |
                ((unsigned int)__half_as_ushort(__float2half_rn(p)) << 16);
        }
        return;
    }

    // ---- node GEMM ----
    const int n0 = (bid >> 1) * 16;            // 3125 stripes * 16 = 50000
    const int w  = threadIdx.x >> 6;           // wave 0..3 (uniform per wave)
    const int l  = threadIdx.x & 63;
    const int lr = l & 15;
    const int kb = l >> 4;                     // k-block 0..3
    const int t0 = w * 4;                      // first tile of this wave

    f16x8 a[4];
    const float* xr = x + (size_t)(n0 + lr) * FIN + kb * 8;
    #pragma unroll
    for (int ks = 0; ks < 4; ++ks) {
        float4 u0 = *reinterpret_cast<const float4*>(xr + ks * 32);
        float4 u1 = *reinterpret_cast<const float4*>(xr + ks * 32 + 4);
        a[ks][0] = (_Float16)u0.x; a[ks][1] = (_Float16)u0.y;
        a[ks][2] = (_Float16)u0.z; a[ks][3] = (_Float16)u0.w;
        a[ks][4] = (_Float16)u1.x; a[ks][5] = (_Float16)u1.y;
        a[ks][6] = (_Float16)u1.z; a[ks][7] = (_Float16)u1.w;
    }

    f32x4 acc[4];
    #pragma unroll
    for (int i = 0; i < 4; ++i) acc[i] = (f32x4){0.f, 0.f, 0.f, 0.f};
    f32x4 acc16 = (f32x4){0.f, 0.f, 0.f, 0.f};

    const _Float16* wb = Wh + (size_t)lr * FIN + kb * 8;
    #pragma unroll
    for (int i = 0; i < 4; ++i) {
        const _Float16* wt = wb + (size_t)(t0 + i) * 16 * FIN;
        #pragma unroll
        for (int ks = 0; ks < 4; ++ks) {
            f16x8 b = *reinterpret_cast<const f16x8*>(wt + ks * 32);
            acc[i] = __builtin_amdgcn_mfma_f32_16x16x32_f16(a[ks], b, acc[i], 0, 0, 0);
        }
    }
    if (w == 3) {
        const _Float16* wt = wb + (size_t)16 * 16 * FIN;
        #pragma unroll
        for (int ks = 0; ks < 4; ++ks) {
            f16x8 b = *reinterpret_cast<const f16x8*>(wt + ks * 32);
            acc16 = __builtin_amdgcn_mfma_f32_16x16x32_f16(a[ks], b, acc16, 0, 0, 0);
        }
    }

    #pragma unroll
    for (int r = 0; r < 4; ++r) {
        const int n = n0 + kb * 4 + r;
        if (t0 < 8) {
            #pragma unroll
            for (int i = 0; i < 4; ++i)
                projA[(size_t)n * HF + (t0 + i) * FO + lr] =
                    __float2half_rn(acc[i][r]);
        } else {
            #pragma unroll
            for (int i = 0; i < 4; ++i) {
                const int o = (t0 + i - 8) * 16 + lr;
                out[(size_t)n * HF + o] = acc[i][r] + bias[o];
            }
        }
        if (w == 3) s_pair[n * 16 + lr] = acc16[r];
    }
}

// ---------------------------------------------------------------------------
// Fused gather: one wave per node; lanes = 8 heads x 8 feature-pairs.
// All lanes share the node's edge range (zero divergence, zero shuffles).
// Per edge: spk dword (broadcast) + s_pair[s] gather + projA[s] 256B
// contiguous wave-read; score+exp inline. 4 independent chains for MLP.
// ---------------------------------------------------------------------------
__global__ __launch_bounds__(256) void k_gather(
    const unsigned int* __restrict__ spk, const int* __restrict__ pos,
    const float* __restrict__ s_pair, const float* __restrict__ ctp,
    const __half2* __restrict__ projA, float* __restrict__ out)
{
    const int wv   = threadIdx.x >> 6;
    const int n    = blockIdx.x * 4 + wv;      // 12500*4 = 50000 exactly
    const int lane = threadIdx.x & 63;
    const int h    = lane >> 3;                // head 0..7
    const int f2   = lane & 7;                 // feature pair 0..7

    const int jb = (n == 0) ? 0 : pos[n - 1];
    const int je = pos[n];
    const float st  = s_pair[n * 16 + 8 + h];
    const float cth = ctp[h];
    const float* __restrict__ ssl = s_pair + h;          // [s*16]
    const __half2* __restrict__ pA = projA + h * 8 + f2; // [s*64]

    float num0 = 0.f, num1 = 0.f, den = 0.f;
    int j = jb;
    for (; j + 3 < je; j += 4) {               // 4 independent chains
        const unsigned int pk0 = spk[j];
        const unsigned int pk1 = spk[j + 1];
        const unsigned int pk2 = spk[j + 2];
        const unsigned int pk3 = spk[j + 3];
        const int s0 = pk0 & 0xFFFF, s1 = pk1 & 0xFFFF;
        const int s2 = pk2 & 0xFFFF, s3 = pk3 & 0xFFFF;
        const float ss0 = ssl[s0 * 16], ss1 = ssl[s1 * 16];
        const float ss2 = ssl[s2 * 16], ss3 = ssl[s3 * 16];
        const __half2 g0 = pA[s0 * 64], g1 = pA[s1 * 64];
        const __half2 g2 = pA[s2 * 64], g3 = pA[s3 * 64];
        const float p0 = __half2float(__ushort_as_half((unsigned short)(pk0 >> 16)));
        const float p1 = __half2float(__ushort_as_half((unsigned short)(pk1 >> 16)));
        const float p2 = __half2float(__ushort_as_half((unsigned short)(pk2 >> 16)));
        const float p3 = __half2float(__ushort_as_half((unsigned short)(pk3 >> 16)));
        float sc0 = ss0 + st + cth * p0;
        float sc1 = ss1 + st + cth * p1;
        float sc2 = ss2 + st + cth * p2;
        float sc3 = ss3 + st + cth * p3;
        sc0 = fmaxf(sc0, 0.2f * sc0);          // leaky_relu(0.2)
        sc1 = fmaxf(sc1, 0.2f * sc1);
        sc2 = fmaxf(sc2, 0.2f * sc2);
        sc3 = fmaxf(sc3, 0.2f * sc3);
        const float ev0 = __expf(sc0), ev1 = __expf(sc1);
        const float ev2 = __expf(sc2), ev3 = __expf(sc3);
        const float2 G0 = __half22float2(g0), G1 = __half22float2(g1);
        const float2 G2 = __half22float2(g2), G3 = __half22float2(g3);
        den  += (ev0 + ev1) + (ev2 + ev3);
        num0 += ev0 * G0.x + ev1 * G1.x + ev2 * G2.x + ev3 * G3.x;
        num1 += ev0 * G0.y + ev1 * G1.y + ev2 * G2.y + ev3 * G3.y;
    }
    for (; j < je; ++j) {
        const unsigned int pk = spk[j];
        const int s = pk & 0xFFFF;
        const float p = __half2float(__ushort_as_half((unsigned short)(pk >> 16)));
        float sc = ssl[s * 16] + st + cth * p;
        sc = fmaxf(sc, 0.2f * sc);
        const float ev = __expf(sc);
        const float2 G = __half22float2(pA[s * 64]);
        den  += ev;
        num0 += ev * G.x;
        num1 += ev * G.y;
    }

    const float inv = 1.f / (den + 1e-16f);
    const int idx = n * HF + h * FO + f2 * 2;
    float2 o = *reinterpret_cast<const float2*>(&out[idx]);  // skip+bias
    float v0 = o.x + num0 * inv;
    float v1 = o.y + num1 * inv;
    v0 = v0 > 0.f ? v0 : expm1f(v0);
    v1 = v1 > 0.f ? v1 : expm1f(v1);
    *reinterpret_cast<float2*>(&out[idx]) = make_float2(v0, v1);
}

// ---------------------------------------------------------------------------
extern "C" void kernel_launch(void* const* d_in, const int* in_sizes, int n_in,
                              void* d_out, int out_size, void* d_ws, size_t ws_size,
                              hipStream_t stream)
{
    const float* x     = (const float*)d_in[0];
    const int*   ei    = (const int*)d_in[1];
    const float* prob  = (const float*)d_in[2];
    const float* Wp    = (const float*)d_in[3];
    const float* Wt    = (const float*)d_in[4];
    const float* a_src = (const float*)d_in[5];
    const float* a_trg = (const float*)d_in[6];
    const float* a_tp  = (const float*)d_in[7];
    const float* Wskip = (const float*)d_in[8];
    const float* bias  = (const float*)d_in[9];
    float* out = (float*)d_out;

    const int E = in_sizes[2];        // edge_prob element count = E
    const int* src = ei;              // edge_index row 0
    const int* trg = ei + E;          // edge_index row 1

    // Workspace layout (~20 MB); all blocks 16B-aligned by construction
    char* wsb = (char*)d_ws;
    __half* projA  = (__half*)wsb;                      // Nn*HF f16 (12.8 MB)
    float* s_pair  = (float*)(wsb + (size_t)Nn*HF*2);   // Nn*16     (3.2 MB)
    float* ctp     = s_pair + (size_t)Nn * 16;          // 16 floats
    _Float16* Wh   = (_Float16*)(ctp + 16);             // 272*128   (68 KB)
    unsigned int* spk = (unsigned int*)(Wh + (size_t)NWR * FIN); // E (3.2 MB)
    int*   deg     = (int*)(spk + E);                   // Nn
    int*   pos     = deg + Nn;                          // Nn
    int*   partial = pos + Nn;                          // NSCAN (pad 256)

    const int nbCount = (E + 255) / 256;                // 3125 (1 edge/thread)
    const int nbFill  = (E + 255) / 256;                // 3125 (1 edge/thread)

    hipMemsetAsync(deg, 0, (size_t)Nn * sizeof(int), stream);
    k_pc<<<NPREP + nbCount, 256, 0, stream>>>(Wp, Wskip, a_src, a_trg, Wt,
                                              a_tp, Wh, ctp, trg, deg, E);
    k_scan1<<<NSCAN, 256, 0, stream>>>(deg, partial);
    k_scan3<<<NSCAN, 256, 0, stream>>>(deg, partial, pos);
    k_fn<<<nbFill + NSTRIPE, 256, 0, stream>>>(src, trg, prob, pos, spk,
                                               x, Wh, bias, projA, out,
                                               s_pair, E);
    k_gather<<<Nn / 4, 256, 0, stream>>>(spk, pos, s_pair, ctp,
                                         (const __half2*)projA, out);
}

// Round 15
// 137.956 us; speedup vs baseline: 1.3715x; 1.2904x over previous
//
#include <hip/hip_runtime.h>
#include <hip/hip_fp16.h>
#include <math.h>

// Problem constants (from reference)
constexpr int Nn  = 50000;   // nodes
constexpr int FIN = 128;     // input features
constexpr int NH  = 8;       // heads
constexpr int FO  = 16;      // features per head
constexpr int HF  = 128;     // NH*FO
constexpr int NWR = 272;     // Wh rows: Wp(128) | Wskip(128) | Va_src(8) | Va_trg(8)
constexpr int NPREP = NWR / 2;                  // 136 prep blocks (2 rows each)
constexpr int NBLK64 = (Nn + 63) / 64;          // 782 node blocks (64 nodes ea)
constexpr int NSCAN = (Nn + 255) / 256;         // 196 scan blocks

typedef _Float16 f16x8 __attribute__((ext_vector_type(8)));
typedef float    f32x4 __attribute__((ext_vector_type(4)));

// ---------------------------------------------------------------------------
// Fused prep + count-with-rank.
//   blocks [0, NPREP)   : Wh[272][128] f16 (2 rows/block) + ctp (block 0)
//   blocks [NPREP, ...) : rank[e] = atomicAdd(deg[trg[e]], 1)  (1 edge/thread)
// The returning atomic does double duty: degree count AND within-row rank,
// so the later fill pass needs NO atomics at all.
// ---------------------------------------------------------------------------
__global__ __launch_bounds__(256) void k_pc(
    const float* __restrict__ Wp, const float* __restrict__ Wskip,
    const float* __restrict__ a_src, const float* __restrict__ a_trg,
    const float* __restrict__ Wt, const float* __restrict__ a_tp,
    _Float16* __restrict__ Wh, float* __restrict__ ctp,
    const int* __restrict__ trg, int* __restrict__ deg,
    int* __restrict__ rank, int E)
{
    const int bid = blockIdx.x;
    if (bid < NPREP) {
        if (bid == 0 && threadIdx.x < NH) {
            int h = threadIdx.x;
            float s = 0.f;
            #pragma unroll
            for (int f = 0; f < FO; ++f) s += Wt[h * FO + f] * a_tp[h * FO + f];
            ctp[h] = s;
        }
        const int o = bid * 2 + (threadIdx.x >> 7);  // 0..271
        const int k = threadIdx.x & 127;
        float v;
        if (o < 128)      v = Wp[o * FIN + k];
        else if (o < 256) v = Wskip[(o - 128) * FIN + k];
        else if (o < 264) {
            const int h = o - 256;
            float s = 0.f;
            #pragma unroll
            for (int f = 0; f < FO; ++f)
                s += a_src[h * FO + f] * Wp[(h * FO + f) * FIN + k];
            v = s;
        } else {
            const int h = o - 264;
            float s = 0.f;
            #pragma unroll
            for (int f = 0; f < FO; ++f)
                s += a_trg[h * FO + f] * Wp[(h * FO + f) * FIN + k];
            v = s;
        }
        Wh[o * FIN + k] = (_Float16)v;
        return;
    }

    int e = (bid - NPREP) * 256 + threadIdx.x;
    if (e < E) rank[e] = atomicAdd(&deg[trg[e]], 1);
}

// ---------------------------------------------------------------------------
// Scan: per-block sums, then fused (redundant block-scan of partials) +
// per-element exclusive scan -> pos (pos stays EXCLUSIVE; row n spans
// [pos[n], n+1<Nn ? pos[n+1] : E) ).
// ---------------------------------------------------------------------------
__global__ __launch_bounds__(256) void k_scan1(const int* __restrict__ deg,
                                               int* __restrict__ partial)
{
    __shared__ int lds[256];
    int t = threadIdx.x, i = blockIdx.x * 256 + t;
    lds[t] = (i < Nn) ? deg[i] : 0;
    __syncthreads();
    for (int off = 128; off > 0; off >>= 1) {
        if (t < off) lds[t] += lds[t + off];
        __syncthreads();
    }
    if (t == 0) partial[blockIdx.x] = lds[0];
}

__global__ __launch_bounds__(256) void k_scan3(const int* __restrict__ deg,
                                               const int* __restrict__ partial,
                                               int* __restrict__ pos)
{
    __shared__ int lds[256], lds2[256];
    const int t = threadIdx.x;
    const int i = blockIdx.x * 256 + t;
    lds2[t] = (t < NSCAN) ? partial[t] : 0;
    __syncthreads();
    for (int off = 1; off < 256; off <<= 1) {
        int u = (t >= off) ? lds2[t - off] : 0;
        __syncthreads();
        lds2[t] += u;
        __syncthreads();
    }
    const int base = (blockIdx.x == 0) ? 0 : lds2[blockIdx.x - 1];
    int v = (i < Nn) ? deg[i] : 0;
    lds[t] = v;
    __syncthreads();
    for (int off = 1; off < 256; off <<= 1) {
        int u = (t >= off) ? lds[t - off] : 0;
        __syncthreads();
        lds[t] += u;
        __syncthreads();
    }
    if (i < Nn) pos[i] = base + lds[t] - v;
}

// ---------------------------------------------------------------------------
// Fused fill + node GEMM (concatenated ranges; fill is now atomic-free and
// short, fusion just saves a launch).
//   blocks [0, nbFill)  : fill — slot = pos[trg]+rank (NO atomics);
//                         spk = src(16b) | f16(prob)(16b), 4 edges/thread.
//   blocks [nbFill, ...) : node GEMM, 64 nodes per block, B-frags in
//                          REGISTERS (loaded once per wave, reused over 4
//                          node-groups -> 4x less L2 B-traffic than 16/wave).
// ---------------------------------------------------------------------------
__global__ __launch_bounds__(256) void k_fn(
    const int* __restrict__ src, const int* __restrict__ trg,
    const float* __restrict__ prob, const int* __restrict__ rank,
    const int* __restrict__ pos, unsigned int* __restrict__ spk,
    const float* __restrict__ x, const _Float16* __restrict__ Wh,
    const float* __restrict__ bias,
    __half* __restrict__ projA, float* __restrict__ out,
    float* __restrict__ s_pair, int E, int nbFill)
{
    const int bid = blockIdx.x;

    if (bid < nbFill) {
        int e4 = bid * 256 + threadIdx.x;
        if (e4 * 4 < E) {
            int4   s4 = reinterpret_cast<const int4*>(src)[e4];
            int4   t4 = reinterpret_cast<const int4*>(trg)[e4];
            float4 p4 = reinterpret_cast<const float4*>(prob)[e4];
            int4   r4 = reinterpret_cast<const int4*>(rank)[e4];
            int    sv[4] = {s4.x, s4.y, s4.z, s4.w};
            int    tv[4] = {t4.x, t4.y, t4.z, t4.w};
            int    rv[4] = {r4.x, r4.y, r4.z, r4.w};
            float  pv[4] = {p4.x, p4.y, p4.z, p4.w};
            #pragma unroll
            for (int i = 0; i < 4; ++i) {
                int slot = pos[tv[i]] + rv[i];
                spk[slot] = (unsigned int)sv[i] |
                    ((unsigned int)__half_as_ushort(__float2half_rn(pv[i])) << 16);
            }
        }
        return;
    }

    // ---- node GEMM: 64 nodes per block, 4 waves; wave w owns tiles
    //      w*4..w*4+3 (wave 3 also the score tile). B in registers. ----
    const int g0 = (bid - nbFill) * 64;
    const int w  = threadIdx.x >> 6;           // wave 0..3 (uniform per wave)
    const int l  = threadIdx.x & 63;
    const int lr = l & 15;
    const int kb = l >> 4;                     // k-block 0..3
    const int t0 = w * 4;                      // first tile of this wave

    // B fragments: loaded ONCE, reused across 4 node-groups
    f16x8 b[4][4];
    const _Float16* wb = Wh + (size_t)lr * FIN + kb * 8;
    #pragma unroll
    for (int i = 0; i < 4; ++i) {
        #pragma unroll
        for (int ks = 0; ks < 4; ++ks)
            b[i][ks] = *reinterpret_cast<const f16x8*>(
                wb + (size_t)(t0 + i) * 16 * FIN + ks * 32);
    }
    f16x8 b16[4];
    if (w == 3) {
        #pragma unroll
        for (int ks = 0; ks < 4; ++ks)
            b16[ks] = *reinterpret_cast<const f16x8*>(
                wb + (size_t)16 * 16 * FIN + ks * 32);
    }

    #pragma unroll
    for (int ng = 0; ng < 4; ++ng) {
        const int n0 = g0 + ng * 16;
        if (n0 >= Nn) break;                   // Nn multiple of 16

        f16x8 a[4];
        const float* xr = x + (size_t)(n0 + lr) * FIN + kb * 8;
        #pragma unroll
        for (int ks = 0; ks < 4; ++ks) {
            float4 u0 = *reinterpret_cast<const float4*>(xr + ks * 32);
            float4 u1 = *reinterpret_cast<const float4*>(xr + ks * 32 + 4);
            a[ks][0] = (_Float16)u0.x; a[ks][1] = (_Float16)u0.y;
            a[ks][2] = (_Float16)u0.z; a[ks][3] = (_Float16)u0.w;
            a[ks][4] = (_Float16)u1.x; a[ks][5] = (_Float16)u1.y;
            a[ks][6] = (_Float16)u1.z; a[ks][7] = (_Float16)u1.w;
        }

        f32x4 acc[4];
        #pragma unroll
        for (int i = 0; i < 4; ++i) acc[i] = (f32x4){0.f, 0.f, 0.f, 0.f};
        f32x4 acc16 = (f32x4){0.f, 0.f, 0.f, 0.f};

        #pragma unroll
        for (int i = 0; i < 4; ++i) {
            #pragma unroll
            for (int ks = 0; ks < 4; ++ks)
                acc[i] = __builtin_amdgcn_mfma_f32_16x16x32_f16(
                    a[ks], b[i][ks], acc[i], 0, 0, 0);
        }
        if (w == 3) {
            #pragma unroll
            for (int ks = 0; ks < 4; ++ks)
                acc16 = __builtin_amdgcn_mfma_f32_16x16x32_f16(
                    a[ks], b16[ks], acc16, 0, 0, 0);
        }

        #pragma unroll
        for (int r = 0; r < 4; ++r) {
            const int n = n0 + kb * 4 + r;
            if (t0 < 8) {
                #pragma unroll
                for (int i = 0; i < 4; ++i)
                    projA[(size_t)n * HF + (t0 + i) * FO + lr] =
                        __float2half_rn(acc[i][r]);
            } else {
                #pragma unroll
                for (int i = 0; i < 4; ++i) {
                    const int o = (t0 + i - 8) * 16 + lr;
                    out[(size_t)n * HF + o] = acc[i][r] + bias[o];
                }
            }
            if (w == 3) s_pair[n * 16 + lr] = acc16[r];
        }
    }
}

// ---------------------------------------------------------------------------
// Fused gather: one wave per node; lanes = 8 heads x 8 feature-pairs.
// All lanes share the node's edge range (zero divergence, zero shuffles).
// Per edge: spk dword (broadcast) + s_pair[s] gather + projA[s] 256B
// contiguous wave-read; score+exp inline. 4 independent chains for MLP.
// ---------------------------------------------------------------------------
__global__ __launch_bounds__(256) void k_gather(
    const unsigned int* __restrict__ spk, const int* __restrict__ pos,
    const float* __restrict__ s_pair, const float* __restrict__ ctp,
    const __half2* __restrict__ projA, float* __restrict__ out, int E)
{
    const int wv   = threadIdx.x >> 6;
    const int n    = blockIdx.x * 4 + wv;      // 12500*4 = 50000 exactly
    const int lane = threadIdx.x & 63;
    const int h    = lane >> 3;                // head 0..7
    const int f2   = lane & 7;                 // feature pair 0..7

    const int jb = pos[n];                     // exclusive prefix
    const int je = (n + 1 < Nn) ? pos[n + 1] : E;
    const float st  = s_pair[n * 16 + 8 + h];
    const float cth = ctp[h];
    const float* __restrict__ ssl = s_pair + h;          // [s*16]
    const __half2* __restrict__ pA = projA + h * 8 + f2; // [s*64]

    float num0 = 0.f, num1 = 0.f, den = 0.f;
    int j = jb;
    for (; j + 3 < je; j += 4) {               // 4 independent chains
        const unsigned int pk0 = spk[j];
        const unsigned int pk1 = spk[j + 1];
        const unsigned int pk2 = spk[j + 2];
        const unsigned int pk3 = spk[j + 3];
        const int s0 = pk0 & 0xFFFF, s1 = pk1 & 0xFFFF;
        const int s2 = pk2 & 0xFFFF, s3 = pk3 & 0xFFFF;
        const float ss0 = ssl[s0 * 16], ss1 = ssl[s1 * 16];
        const float ss2 = ssl[s2 * 16], ss3 = ssl[s3 * 16];
        const __half2 g0 = pA[s0 * 64], g1 = pA[s1 * 64];
        const __half2 g2 = pA[s2 * 64], g3 = pA[s3 * 64];
        const float p0 = __half2float(__ushort_as_half((unsigned short)(pk0 >> 16)));
        const float p1 = __half2float(__ushort_as_half((unsigned short)(pk1 >> 16)));
        const float p2 = __half2float(__ushort_as_half((unsigned short)(pk2 >> 16)));
        const float p3 = __half2float(__ushort_as_half((unsigned short)(pk3 >> 16)));
        float sc0 = ss0 + st + cth * p0;
        float sc1 = ss1 + st + cth * p1;
        float sc2 = ss2 + st + cth * p2;
        float sc3 = ss3 + st + cth * p3;
        sc0 = fmaxf(sc0, 0.2f * sc0);          // leaky_relu(0.2)
        sc1 = fmaxf(sc1, 0.2f * sc1);
        sc2 = fmaxf(sc2, 0.2f * sc2);
        sc3 = fmaxf(sc3, 0.2f * sc3);
        const float ev0 = __expf(sc0), ev1 = __expf(sc1);
        const float ev2 = __expf(sc2), ev3 = __expf(sc3);
        const float2 G0 = __half22float2(g0), G1 = __half22float2(g1);
        const float2 G2 = __half22float2(g2), G3 = __half22float2(g3);
        den  += (ev0 + ev1) + (ev2 + ev3);
        num0 += ev0 * G0.x + ev1 * G1.x + ev2 * G2.x + ev3 * G3.x;
        num1 += ev0 * G0.y + ev1 * G1.y + ev2 * G2.y + ev3 * G3.y;
    }
    for (; j < je; ++j) {
        const unsigned int pk = spk[j];
        const int s = pk & 0xFFFF;
        const float p = __half2float(__ushort_as_half((unsigned short)(pk >> 16)));
        float sc = ssl[s * 16] + st + cth * p;
        sc = fmaxf(sc, 0.2f * sc);
        const float ev = __expf(sc);
        const float2 G = __half22float2(pA[s * 64]);
        den  += ev;
        num0 += ev * G.x;
        num1 += ev * G.y;
    }

    const float inv = 1.f / (den + 1e-16f);
    const int idx = n * HF + h * FO + f2 * 2;
    float2 o = *reinterpret_cast<const float2*>(&out[idx]);  // skip+bias
    float v0 = o.x + num0 * inv;
    float v1 = o.y + num1 * inv;
    v0 = v0 > 0.f ? v0 : expm1f(v0);
    v1 = v1 > 0.f ? v1 : expm1f(v1);
    *reinterpret_cast<float2*>(&out[idx]) = make_float2(v0, v1);
}

// ---------------------------------------------------------------------------
extern "C" void kernel_launch(void* const* d_in, const int* in_sizes, int n_in,
                              void* d_out, int out_size, void* d_ws, size_t ws_size,
                              hipStream_t stream)
{
    const float* x     = (const float*)d_in[0];
    const int*   ei    = (const int*)d_in[1];
    const float* prob  = (const float*)d_in[2];
    const float* Wp    = (const float*)d_in[3];
    const float* Wt    = (const float*)d_in[4];
    const float* a_src = (const float*)d_in[5];
    const float* a_trg = (const float*)d_in[6];
    const float* a_tp  = (const float*)d_in[7];
    const float* Wskip = (const float*)d_in[8];
    const float* bias  = (const float*)d_in[9];
    float* out = (float*)d_out;

    const int E = in_sizes[2];        // edge_prob element count = E
    const int* src = ei;              // edge_index row 0
    const int* trg = ei + E;          // edge_index row 1

    // Workspace layout (~27 MB); all blocks 16B-aligned by construction
    char* wsb = (char*)d_ws;
    __half* projA  = (__half*)wsb;                      // Nn*HF f16 (12.8 MB)
    float* s_pair  = (float*)(wsb + (size_t)Nn*HF*2);   // Nn*16     (3.2 MB)
    float* ctp     = s_pair + (size_t)Nn * 16;          // 16 floats
    _Float16* Wh   = (_Float16*)(ctp + 16);             // 272*128   (68 KB)
    unsigned int* spk = (unsigned int*)(Wh + (size_t)NWR * FIN); // E (3.2 MB)
    int*   rank    = (int*)(spk + E);                   // E         (3.2 MB)
    int*   deg     = rank + E;                          // Nn
    int*   pos     = deg + Nn;                          // Nn
    int*   partial = pos + Nn;                          // NSCAN (pad 256)

    const int nbCount = (E + 255) / 256;                // 3125 (1 edge/thread)
    const int nbFill  = (E + 1023) / 1024;              // 782  (4 edges/thread)

    hipMemsetAsync(deg, 0, (size_t)Nn * sizeof(int), stream);
    k_pc<<<NPREP + nbCount, 256, 0, stream>>>(Wp, Wskip, a_src, a_trg, Wt,
                                              a_tp, Wh, ctp, trg, deg, rank, E);
    k_scan1<<<NSCAN, 256, 0, stream>>>(deg, partial);
    k_scan3<<<NSCAN, 256, 0, stream>>>(deg, partial, pos);
    k_fn<<<nbFill + NBLK64, 256, 0, stream>>>(src, trg, prob, rank, pos, spk,
                                              x, Wh, bias, projA, out,
                                              s_pair, E, nbFill);
    k_gather<<<Nn / 4, 256, 0, stream>>>(spk, pos, s_pair, ctp,
                                         (const __half2*)projA, out, E);
}